// Round 6
// baseline (246.731 us; speedup 1.0000x reference)
//
#include <hip/hip_runtime.h>

// BioConvolution: 256 per-location GEMMs, C_l(64x128) = A_l(64x1024)*B_l(1024x128)+bias, ReLU
// X[n,h,w,ch] strides: n=262144, h=4096, w=64, ch=1.
// A_l[n][k] = X[n, r*4+i, c*4+j, ch], k = i*256+j*64+ch = s*64+ch for step s=i*4+j
// B_l[k][f] = Fw[l*131072 + k*128 + f]
//
// R6: async-pinned B stream. grid 512: (l = bx&255, f-half = bx>>8); block 512 thr
// (8 waves: wf = w&3 -> 16-col slice, wn = w>>2 -> 32-row half). 2 blocks/CU.
// B: __builtin_amdgcn_global_load_lds size=4 (256 B = one 64-col half k-row per instr),
//    fp32 into LDS rows padded to 65 floats (2-way bank aliasing = free), double-buffered;
//    issued for step s+1 right after the barrier, drained by the NEXT barrier's vmcnt(0)
//    -> a full step of HBM service always in flight; compiler cannot sink these.
// A: per-lane direct global->reg (frag = 8 contiguous floats); 4 f-sibling waves share
//    rows -> L1 dedup. Convert fp32->bf16 in VALU, MFMA 16x16x32 accumulate fp32.

typedef __bf16 bf16x8 __attribute__((ext_vector_type(8)));
typedef float f32x4 __attribute__((ext_vector_type(4)));

#define SB 65  // LDS B row stride in floats (64 + 1 pad)

__device__ __forceinline__ unsigned pack2(float a, float b) {
  __bf16 lo = (__bf16)a, hi = (__bf16)b;
  return (unsigned)__builtin_bit_cast(unsigned short, lo) |
         ((unsigned)__builtin_bit_cast(unsigned short, hi) << 16);
}
__device__ __forceinline__ bf16x8 cvt8(float4 lo, float4 hi) {
  uint4 v;
  v.x = pack2(lo.x, lo.y);
  v.y = pack2(lo.z, lo.w);
  v.z = pack2(hi.x, hi.y);
  v.w = pack2(hi.z, hi.w);
  return __builtin_bit_cast(bf16x8, v);
}
__device__ __forceinline__ void gl_lds4(const float* g, float* lds) {
  __builtin_amdgcn_global_load_lds(
      (const __attribute__((address_space(1))) void*)g,
      (__attribute__((address_space(3))) void*)lds, 4, 0, 0);
}

__global__ __launch_bounds__(512, 4) void bioconv_async(
    const float* __restrict__ X, const float* __restrict__ Fw,
    const float* __restrict__ bias, float* __restrict__ out) {
  const int bx = blockIdx.x;
  const int l = bx & 255;   // location
  const int fh = bx >> 8;   // f half: cols [fh*64, fh*64+64)
  const int r = l >> 4, c = l & 15;
  const int t = threadIdx.x;
  const int w = t >> 6;     // wave 0..7
  const int wf = w & 3;     // f-slice [wf*16, wf*16+16) within the half
  const int wn = w >> 2;    // n-half: rows [wn*32, wn*32+32)
  const int lane = t & 63;
  const int q = lane >> 4, nl = lane & 15;

  __shared__ __align__(16) float Bs[2][64 * SB];  // 2 x 16.6 KB fp32 (padded rows)

  // A row bases: rows wn*32 + mb*16 + nl; q*8 = ch sub-offset
  const float* pA[2];
#pragma unroll
  for (int mb = 0; mb < 2; ++mb)
    pA[mb] = X + (size_t)(wn * 32 + mb * 16 + nl) * 262144 + r * 16384 + c * 256 + q * 8;

  // B async source: wave w owns k-rows [w*8, w*8+8); per-lane addr = row + lane
  const int kw = w * 8;
  const float* pB = Fw + (size_t)l * 131072 + fh * 64 + (size_t)kw * 128 + lane;

  f32x4 acc[2];
  acc[0] = (f32x4){0.f, 0.f, 0.f, 0.f};
  acc[1] = (f32x4){0.f, 0.f, 0.f, 0.f};

  auto issueB = [&](int s, int buf) {
    const float* g = pB + (size_t)s * 8192;  // step s -> k = s*64 + kw + i
    float* ldsrow = &Bs[buf][kw * SB];
#pragma unroll
    for (int i = 0; i < 8; ++i)
      gl_lds4(g + i * 128, ldsrow + i * SB);  // 256 B: half k-row, lands base+lane*4
  };

  // preamble: stage step 0, drain, enter loop
  issueB(0, 0);
  __syncthreads();

  for (int s = 0; s < 16; ++s) {
    if (s + 1 < 16) issueB(s + 1, (s + 1) & 1);  // in flight across this whole step

    // A fragments for step s (plain loads; L1-shared by 4 f-sibling waves)
    const int pixoff = (s >> 2) * 4096 + (s & 3) * 64;
    bf16x8 af[2][2];  // [kc][mb]
#pragma unroll
    for (int mb = 0; mb < 2; ++mb) {
      float4 lo0 = *(const float4*)(pA[mb] + pixoff);
      float4 hi0 = *(const float4*)(pA[mb] + pixoff + 4);
      float4 lo1 = *(const float4*)(pA[mb] + pixoff + 32);
      float4 hi1 = *(const float4*)(pA[mb] + pixoff + 36);
      af[0][mb] = cvt8(lo0, hi0);
      af[1][mb] = cvt8(lo1, hi1);
    }

    // B fragments from LDS (ready: drained at previous barrier) + MFMA
    const int buf = s & 1;
#pragma unroll
    for (int kc = 0; kc < 2; ++kc) {
      const float* bp = &Bs[buf][(kc * 32 + q * 8) * SB + wf * 16 + nl];
      uint4 bw;
      bw.x = pack2(bp[0], bp[SB]);
      bw.y = pack2(bp[2 * SB], bp[3 * SB]);
      bw.z = pack2(bp[4 * SB], bp[5 * SB]);
      bw.w = pack2(bp[6 * SB], bp[7 * SB]);
      bf16x8 bfr = __builtin_bit_cast(bf16x8, bw);
      acc[0] = __builtin_amdgcn_mfma_f32_16x16x32_bf16(af[kc][0], bfr, acc[0], 0, 0, 0);
      acc[1] = __builtin_amdgcn_mfma_f32_16x16x32_bf16(af[kc][1], bfr, acc[1], 0, 0, 0);
    }

    __syncthreads();  // vmcnt(0): drains B(s+1); protects buffer reuse
  }

  // epilogue: bias + ReLU; D layout row = q*4 + reg, col = nl
  const int f = fh * 64 + wf * 16 + nl;
  const float bv = bias[f];
  float* ob = out + (size_t)l * 128 + f;
#pragma unroll
  for (int mb = 0; mb < 2; ++mb) {
#pragma unroll
    for (int v = 0; v < 4; ++v) {
      const int row = wn * 32 + mb * 16 + q * 4 + v;
      ob[(size_t)row * 32768] = fmaxf(acc[mb][v] + bv, 0.f);
    }
  }
}

extern "C" void kernel_launch(void* const* d_in, const int* in_sizes, int n_in,
                              void* d_out, int out_size, void* d_ws, size_t ws_size,
                              hipStream_t stream) {
  const float* X = (const float*)d_in[0];
  const float* Fw = (const float*)d_in[1];
  const float* bias = (const float*)d_in[2];
  float* out = (float*)d_out;
  bioconv_async<<<512, 512, 0, stream>>>(X, Fw, bias, out);
}